// Round 1
// baseline (100.975 us; speedup 1.0000x reference)
//
#include <hip/hip_runtime.h>

#define IC 3
#define OCH 16
#define IDD 16
#define IHH 32
#define IWW 32
#define ODD 31
#define OHH 63
#define OWW 63
#define NB 32

// Fused ConvTranspose3d(3->16,k3,s2,p1) + channel-LSE + x*sigmoid(x+3)/6 - bias, clip [-1,1].
// Parity decomposition: each thread computes a 2(oh) x 2(ow) patch at a single od.
//   even coord -> single center tap (k=1), odd coord -> taps k={0,2}. No bounds checks
//   needed for in-range outputs (all derived input indices stay in range); edge
//   (oh=63 / ow=63 don't exist) handled by clamped loads + store guards.
__global__ __launch_bounds__(256) void convt_lse_kernel(
    const float* __restrict__ x, const float* __restrict__ w,
    const float* __restrict__ bias, float* __restrict__ out)
{
    // LDS weights: [ic][kd][kh][kw][oc], oc contiguous for ds_read_b128
    __shared__ float wl[IC * 27 * OCH];
    for (int idx = threadIdx.x; idx < IC * 27 * OCH; idx += 256) {
        int ic   = idx / (27 * OCH);
        int rem  = idx - ic * (27 * OCH);
        int kpos = rem >> 4;   // kd*9 + kh*3 + kw
        int oc   = rem & 15;
        wl[idx] = w[(ic * OCH + oc) * 27 + kpos];
    }
    __syncthreads();

    const int j  = threadIdx.x & 31;                       // ow pair index: ow = 2j, 2j+1
    const int i  = (threadIdx.x >> 5) + (blockIdx.x << 3); // oh pair index: oh = 2i, 2i+1
    const int od = blockIdx.y;                             // [0,31)
    const int b  = blockIdx.z;                             // [0,32)

    // acc[p][oc]: p0=(even,even) p1=(even,odd) p2=(odd,even) p3=(odd,odd)
    float acc[4][OCH];
    #pragma unroll
    for (int p = 0; p < 4; ++p)
        #pragma unroll
        for (int oc = 0; oc < OCH; ++oc) acc[p][oc] = 0.0f;

    const int ih0 = i;
    const int ih1 = min(i + 1, IHH - 1);   // clamped: only feeds non-stored rows at i=31
    const int iw0 = j;
    const int iw1 = min(j + 1, IWW - 1);   // clamped: only feeds non-stored cols at j=31

    auto do_tap = [&](int kd, int id) {
        #pragma unroll
        for (int ic = 0; ic < IC; ++ic) {
            const float* __restrict__ xp = x + (((b * IC + ic) * IDD + id) << 10);
            const float x00 = xp[ih0 * IWW + iw0];
            const float x01 = xp[ih0 * IWW + iw1];
            const float x10 = xp[ih1 * IWW + iw0];
            const float x11 = xp[ih1 * IWW + iw1];
            const float* __restrict__ wp = &wl[(ic * 3 + kd) * 9 * OCH];
            #pragma unroll
            for (int oc = 0; oc < OCH; ++oc) {
                // (even oh, even ow): kh=1,kw=1
                acc[0][oc] = fmaf(x00, wp[4 * OCH + oc], acc[0][oc]);
                // (even, odd): kh=1, kw=0 (x[.][j+1]) + kw=2 (x[.][j])
                acc[1][oc] = fmaf(x01, wp[3 * OCH + oc],
                             fmaf(x00, wp[5 * OCH + oc], acc[1][oc]));
                // (odd, even): kw=1, kh=0 (x[i+1][.]) + kh=2 (x[i][.])
                acc[2][oc] = fmaf(x10, wp[1 * OCH + oc],
                             fmaf(x00, wp[7 * OCH + oc], acc[2][oc]));
                // (odd, odd): (0,0)x11 (0,2)x10 (2,0)x01 (2,2)x00
                acc[3][oc] = fmaf(x11, wp[0 * OCH + oc],
                             fmaf(x10, wp[2 * OCH + oc],
                             fmaf(x01, wp[6 * OCH + oc],
                             fmaf(x00, wp[8 * OCH + oc], acc[3][oc]))));
            }
        }
    };

    if (od & 1) {           // odd od: kd=0 (id=(od+1)/2) and kd=2 (id=(od-1)/2)
        do_tap(0, (od + 1) >> 1);
        do_tap(2, (od - 1) >> 1);
    } else {                // even od: kd=1, id=od/2
        do_tap(1, od >> 1);
    }

    const float bv  = bias[0];
    const int oh0   = 2 * i;
    const int ow0   = 2 * j;
    const int obase = (b * ODD + od) * OHH;

    #pragma unroll
    for (int p = 0; p < 4; ++p) {
        const int oh = oh0 + (p >> 1);
        const int ow = ow0 + (p & 1);
        if (oh < OHH && ow < OWW) {
            float m = acc[p][0];
            #pragma unroll
            for (int oc = 1; oc < OCH; ++oc) m = fmaxf(m, acc[p][oc]);
            float s = 0.0f;
            #pragma unroll
            for (int oc = 0; oc < OCH; ++oc) s += __expf(acc[p][oc] - m);
            const float v  = m + __logf(s);
            const float hs = v / (6.0f * (1.0f + __expf(-(v + 3.0f))));
            const float r  = fminf(1.0f, fmaxf(-1.0f, hs - bv));
            out[(obase + oh) * OWW + ow] = r;
        }
    }
}

extern "C" void kernel_launch(void* const* d_in, const int* in_sizes, int n_in,
                              void* d_out, int out_size, void* d_ws, size_t ws_size,
                              hipStream_t stream) {
    const float* x    = (const float*)d_in[0];
    const float* w    = (const float*)d_in[1];
    const float* bias = (const float*)d_in[2];
    float* out        = (float*)d_out;

    dim3 grid(4, ODD, NB);   // 4 i-chunks (8 i-values each) x od x batch
    dim3 block(256);
    convt_lse_kernel<<<grid, block, 0, stream>>>(x, w, bias, out);
}